// Round 5
// baseline (1793.593 us; speedup 1.0000x reference)
//
#include <hip/hip_runtime.h>
#include <hip/hip_bf16.h>

#define BATCH 8
#define HH 128
#define WW 128
#define CC 256
#define OCC 512

typedef __bf16 bf16x8 __attribute__((ext_vector_type(8)));
typedef unsigned int u32x4 __attribute__((ext_vector_type(4)));
typedef float f32x4 __attribute__((ext_vector_type(4)));

// ws layout (bytes):
//   wt   @ 0           size 2,359,296   (9*512*256 bf16, oc-permuted)
//   zrow @ 2,359,296   size 65,536      (one zero x-row, bf16)
//   xtb  @ 2,424,832   size 67,108,864  (planar bf16 x[b][p][i][j])
//   xbf  @ 69,533,696  size 67,108,864  (NHWC bf16 x[b][i][j][ic])
//   cv   @ 136,642,560 size 268,435,456 (f32 coords cv[b][n][cr][j])
#define WT_OFF   0
#define ZROW_OFF 2359296
#define XTB_OFF  2424832
#define XBF_OFF  69533696
#define CV_OFF   136642560
#define WS_NEED_SPLIT (CV_OFF + 268435456ull)
#define WS_NEED_FUSED (XBF_OFF + 67108864ull)

// Weights: K[tap][ic][oc] (f32 HWIO) -> Wt[tap][n][ic] (bf16), oc permuted:
// n -> oc(n) = 2*(n&255) + (n>>8)  =>  p = n&255, parity = n>>8.
__global__ void prep_weights(const float* __restrict__ k, __bf16* __restrict__ wt) {
    const int n   = blockIdx.x & 511;
    const int tap = blockIdx.x >> 9;
    const int ic  = threadIdx.x;
    const int oc  = ((n & 255) << 1) | (n >> 8);
    wt[((size_t)(tap * OCC + n)) * CC + ic] = (__bf16)k[((size_t)(tap * CC + ic)) * OCC + oc];
}

__global__ void zero_fill(float* __restrict__ z) {
    z[blockIdx.x * 256 + threadIdx.x] = 0.0f;
}

// x (f32 NHWC) -> xbf (bf16 NHWC) and xtb (bf16 planar [b][p][m])
__global__ __launch_bounds__(256)
void prep_x(const float* __restrict__ x, __bf16* __restrict__ xbf, __bf16* __restrict__ xtb) {
    __shared__ float tile[64][65];
    const int pt = blockIdx.x & 3;
    const int mt = (blockIdx.x >> 2) & 255;
    const int b  = blockIdx.x >> 10;
    const int m0 = mt * 64, p0 = pt * 64;
    const int tl = threadIdx.x & 63, tr = threadIdx.x >> 6;

    const float* xb = x + (size_t)b * (HH * WW * CC);
    __bf16* xbfb = xbf + (size_t)b * (HH * WW * CC);
#pragma unroll
    for (int rr = 0; rr < 16; ++rr) {
        const int m = rr * 4 + tr;
        const float v = xb[(size_t)(m0 + m) * CC + p0 + tl];
        tile[m][tl] = v;
        xbfb[(size_t)(m0 + m) * CC + p0 + tl] = (__bf16)v;
    }
    __syncthreads();
    __bf16* xtbb = xtb + (size_t)b * (CC * HH * WW);
#pragma unroll
    for (int rr = 0; rr < 16; ++rr) {
        const int p = rr * 4 + tr;
        xtbb[(size_t)(p0 + p) * (HH * WW) + m0 + tl] = (__bf16)tile[tl][p];
    }
}

__device__ __forceinline__ void gload16(const void* g, void* l) {
    __builtin_amdgcn_global_load_lds(
        (const __attribute__((address_space(1))) void*)g,
        (__attribute__((address_space(3))) void*)l, 16, 0, 0);
}

// Stage one (row, ic-half) chunk: LDS logical [128 col][128 ic] bf16 = 32 KB,
// stored XOR-swizzled (byte ^= (col&7)<<4) via pre-swizzled SOURCE address.
__device__ __forceinline__ void stage_chunk(const __bf16* __restrict__ srcrow, int h,
                                            __bf16* ldsbuf, int wid, int lane) {
    const int sub = lane >> 4;
    const int icb = (lane & 15) * 16;
#pragma unroll
    for (int t = 0; t < 8; ++t) {
        const int col = (wid * 8 + t) * 4 + sub;
        const int srcoff = col * 512 + h * 256 + (icb ^ ((col & 7) << 4));
        gload16((const char*)srcrow + srcoff, (char*)ldsbuf + (wid * 8 + t) * 1024);
    }
}

// ============ SPLIT PATH: kernel A — conv GEMM -> f32 coords ============
// Block = (b, cr, nc). Stores clipped absolute coords into cv[b][n][cr][j]:
// element j holds (j&1)==0 ? row-coord : col-coord for output pixel
// (i2=(cr>>1)+64*par, j2=(cr&1)*64+(j>>1), p=n&255), par=n>>8 (=nc>>1).
__global__ __launch_bounds__(256, 2)
void conv_coords(const __bf16* __restrict__ xbf, const __bf16* __restrict__ zrow,
                 const __bf16* __restrict__ wt, const float* __restrict__ bias,
                 float* __restrict__ cv) {
    __shared__ __bf16 lds_a[2][16384];

    const int orig = blockIdx.x;
    const int bi = (orig & 7) * 512 + (orig >> 3);  // XCD-bijective, nwg=4096
    const int nc = bi & 3;
    const int cr = (bi >> 2) & 127;
    const int b  = bi >> 9;

    const int tid  = threadIdx.x;
    const int lane = tid & 63;
    const int wid  = tid >> 6;
    const int l15  = lane & 15;
    const int lg   = lane >> 4;

    f32x4 acc[2][8] = {};

    {
        const int rg = cr - 1;
        const __bf16* srcrow = ((unsigned)rg < 128u) ? xbf + ((size_t)(b * 128 + rg) << 15) : zrow;
        stage_chunk(srcrow, 0, lds_a[0], wid, lane);
    }
    __syncthreads();

    int cur = 0;
#pragma unroll 1
    for (int idx = 0; idx < 6; ++idx) {
        if (idx < 5) {
            const int n2 = idx + 1;
            const int rg = cr + (n2 >> 1) - 1;
            const __bf16* srcrow = ((unsigned)rg < 128u) ? xbf + ((size_t)(b * 128 + rg) << 15) : zrow;
            stage_chunk(srcrow, n2 & 1, lds_a[cur ^ 1], wid, lane);
        }
        const int r = idx >> 1;
        const int h = idx & 1;
        const __bf16* Ab = lds_a[cur];
        const int colb = wid * 32;

#pragma unroll
        for (int dx = 0; dx < 3; ++dx) {
            const __bf16* wtap = wt + ((size_t)((r * 3 + dx) * OCC + nc * 128)) * CC + h * 128;
#pragma unroll
            for (int kk = 0; kk < 4; ++kk) {
                bf16x8 a[2];
#pragma unroll
                for (int mi = 0; mi < 2; ++mi) {
                    const int ca = colb + mi * 16 + l15 + dx - 1;
                    const unsigned msk = ((unsigned)ca < 128u) ? 0xFFFFFFFFu : 0u;
                    const int ad = (((ca & 127) << 8) + ((kk * 32 + lg * 8) << 1)) ^ ((ca & 7) << 4);
                    u32x4 uv = *(const u32x4*)((const char*)Ab + ad);
                    uv &= msk;
                    a[mi] = __builtin_bit_cast(bf16x8, uv);
                }
#pragma unroll
                for (int ni = 0; ni < 8; ++ni) {
                    const bf16x8 bv = *(const bf16x8*)(wtap + (ni * 16 + l15) * CC + kk * 32 + lg * 8);
                    acc[0][ni] = __builtin_amdgcn_mfma_f32_16x16x32_bf16(a[0], bv, acc[0][ni], 0, 0, 0);
                    acc[1][ni] = __builtin_amdgcn_mfma_f32_16x16x32_bf16(a[1], bv, acc[1][ni], 0, 0, 0);
                }
            }
        }
        __syncthreads();
        cur ^= 1;
    }

    // Epilogue: fold bias + absolute grid + clip, store f32x4 (16B/lane contiguous).
    const int par = nc >> 1;
    const int i2  = (cr >> 1) + (par << 6);
    const int jbase = (cr & 1) << 6;
    const float fi2 = (float)i2;

#pragma unroll
    for (int ni = 0; ni < 8; ++ni) {
        const int n = nc * 128 + ni * 16 + l15;
        const float bv = bias[2 * (n & 255) + par];
        float* cvp = cv + ((((size_t)b * 512 + n) * 128 + cr) << 7);
#pragma unroll
        for (int mi = 0; mi < 2; ++mi) {
            const int j0 = wid * 32 + mi * 16 + lg * 4;
            const int u0 = j0 >> 1;
            f32x4 o;
            o[0] = fminf(fmaxf(acc[mi][ni][0] + bv + fi2, 0.f), 127.f);
            o[1] = fminf(fmaxf(acc[mi][ni][1] + bv + (float)(jbase + u0), 0.f), 127.f);
            o[2] = fminf(fmaxf(acc[mi][ni][2] + bv + fi2, 0.f), 127.f);
            o[3] = fminf(fmaxf(acc[mi][ni][3] + bv + (float)(jbase + u0 + 1), 0.f), 127.f);
            *(f32x4*)(cvp + j0) = o;
        }
    }
}

// ============ SPLIT PATH: kernel B — bilinear gather ============
__device__ __forceinline__ float bilerp(const __bf16* __restrict__ plane, float c0, float c1) {
    const int lt0 = (int)floorf(c0);
    const int rb0 = (int)ceilf(c0);
    const int lt1 = (int)floorf(c1);
    const int rb1 = (int)ceilf(c1);
    const float f0 = c0 - (float)lt0;
    const float f1 = c1 - (float)lt1;
    const float vlt = (float)plane[(lt0 << 7) + lt1];
    const float vrb = (float)plane[(rb0 << 7) + rb1];
    const float vlb = (float)plane[(lt0 << 7) + rb1];
    const float vrt = (float)plane[(rb0 << 7) + lt1];
    const float vt = vlt + (vrt - vlt) * f0;
    const float vb = vlb + (vrb - vlb) * f0;
    return vt + (vb - vt) * f1;
}

// Block (1024 thr, 16 waves) = (b, i2). Wave w at iter `it` handles plane
// p = it*16 + w (16 consecutive p concurrently -> write lines fill).
// Lane reads one f32x4 of cv (covers both conv rows cr_a/cr_a+1), computes
// 2 output pixels (j2a, j2a+1) of plane p.
__global__ __launch_bounds__(1024)
void gather_out(const float* __restrict__ cv, const __bf16* __restrict__ xtb,
                float* __restrict__ out) {
    const int orig = blockIdx.x;
    const int bi = (orig & 7) * 128 + (orig >> 3);  // XCD-bijective, nwg=1024
    const int i2 = bi & 127;
    const int b  = bi >> 7;

    const int tid  = threadIdx.x;
    const int lane = tid & 63;
    const int w    = tid >> 6;  // 0..15

    const int par  = i2 >> 6;
    const int cr_a = (i2 & 63) << 1;
    const int j2a  = ((lane >> 5) << 6) + ((lane & 31) << 1);

    const float* cvb = cv + ((((size_t)b * 512) * 128 + cr_a) << 7);
    float* ob = out + (((size_t)(b * 128 + i2)) << 7) * 256;

#pragma unroll 1
    for (int it = 0; it < 16; ++it) {
        const int p = it * 16 + w;
        const int n = p + (par << 8);
        const f32x4 c = *(const f32x4*)(cvb + ((size_t)n << 14) + lane * 4);
        const __bf16* plane = xtb + ((size_t)(b * 256 + p) << 14);
        const float r0 = bilerp(plane, c[0], c[1]);
        const float r1 = bilerp(plane, c[2], c[3]);
        ob[(size_t)j2a * 256 + p] = r0;
        ob[(size_t)(j2a + 1) * 256 + p] = r1;
    }
}

// ============ FUSED FALLBACK (verified round-4 kernel) ============
__global__ __launch_bounds__(256, 2)
void conv_offset_sample(const __bf16* __restrict__ xbf, const __bf16* __restrict__ xtb,
                        const __bf16* __restrict__ zrow, const __bf16* __restrict__ wt,
                        const float* __restrict__ bias, float* __restrict__ out) {
    __shared__ __bf16 lds_a[2][16384];

    const int orig = blockIdx.x;
    const int bi = (orig & 7) * 512 + (orig >> 3);
    const int nc = bi & 3;
    const int cr = (bi >> 2) & 127;
    const int b  = bi >> 9;

    const int tid  = threadIdx.x;
    const int lane = tid & 63;
    const int wid  = tid >> 6;
    const int l15  = lane & 15;
    const int lg   = lane >> 4;

    f32x4 acc[2][8] = {};

    {
        const int rg = cr - 1;
        const __bf16* srcrow = ((unsigned)rg < 128u) ? xbf + ((size_t)(b * 128 + rg) << 15) : zrow;
        stage_chunk(srcrow, 0, lds_a[0], wid, lane);
    }
    __syncthreads();

    int cur = 0;
#pragma unroll 1
    for (int idx = 0; idx < 6; ++idx) {
        if (idx < 5) {
            const int n2 = idx + 1;
            const int rg = cr + (n2 >> 1) - 1;
            const __bf16* srcrow = ((unsigned)rg < 128u) ? xbf + ((size_t)(b * 128 + rg) << 15) : zrow;
            stage_chunk(srcrow, n2 & 1, lds_a[cur ^ 1], wid, lane);
        }
        const int r = idx >> 1;
        const int h = idx & 1;
        const __bf16* Ab = lds_a[cur];
        const int colb = wid * 32;

#pragma unroll
        for (int dx = 0; dx < 3; ++dx) {
            const __bf16* wtap = wt + ((size_t)((r * 3 + dx) * OCC + nc * 128)) * CC + h * 128;
#pragma unroll
            for (int kk = 0; kk < 4; ++kk) {
                bf16x8 a[2];
#pragma unroll
                for (int mi = 0; mi < 2; ++mi) {
                    const int ca = colb + mi * 16 + l15 + dx - 1;
                    const unsigned msk = ((unsigned)ca < 128u) ? 0xFFFFFFFFu : 0u;
                    const int ad = (((ca & 127) << 8) + ((kk * 32 + lg * 8) << 1)) ^ ((ca & 7) << 4);
                    u32x4 uv = *(const u32x4*)((const char*)Ab + ad);
                    uv &= msk;
                    a[mi] = __builtin_bit_cast(bf16x8, uv);
                }
#pragma unroll
                for (int ni = 0; ni < 8; ++ni) {
                    const bf16x8 bv = *(const bf16x8*)(wtap + (ni * 16 + l15) * CC + kk * 32 + lg * 8);
                    acc[0][ni] = __builtin_amdgcn_mfma_f32_16x16x32_bf16(a[0], bv, acc[0][ni], 0, 0, 0);
                    acc[1][ni] = __builtin_amdgcn_mfma_f32_16x16x32_bf16(a[1], bv, acc[1][ni], 0, 0, 0);
                }
            }
        }
        __syncthreads();
        cur ^= 1;
    }

    const int jbase = (cr & 1) << 6;
    const int par = nc >> 1;
    const int i2  = (cr >> 1) + (par << 6);
    const float fi2 = (float)i2;

#pragma unroll
    for (int ni = 0; ni < 8; ++ni) {
        const int p = ((nc & 1) << 7) + ni * 16 + l15;
        const float bv = bias[2 * p + par];
        const __bf16* plane = xtb + ((size_t)(b * 256 + p) << 14);
        float* op = out + (((size_t)(b * 128 + i2)) << 7) * 256 + p;

#pragma unroll
        for (int mi = 0; mi < 2; ++mi) {
#pragma unroll
            for (int s = 0; s < 2; ++s) {
                const int u  = wid * 16 + mi * 8 + lg * 2 + s;
                const int j2 = jbase + u;

                float c0 = acc[mi][ni][2 * s]     + bv + fi2;
                float c1 = acc[mi][ni][2 * s + 1] + bv + (float)j2;
                c0 = fminf(fmaxf(c0, 0.f), 127.f);
                c1 = fminf(fmaxf(c1, 0.f), 127.f);

                const float r = bilerp(plane, c0, c1);
                op[(size_t)j2 * 256] = r;
            }
        }
    }
}

extern "C" void kernel_launch(void* const* d_in, const int* in_sizes, int n_in,
                              void* d_out, int out_size, void* d_ws, size_t ws_size,
                              hipStream_t stream) {
    const float* x    = (const float*)d_in[0];
    const float* kern = (const float*)d_in[1];
    const float* bias = (const float*)d_in[2];
    float* out = (float*)d_out;

    __bf16* wt   = (__bf16*)((char*)d_ws + WT_OFF);
    __bf16* zrow = (__bf16*)((char*)d_ws + ZROW_OFF);
    __bf16* xtb  = (__bf16*)((char*)d_ws + XTB_OFF);
    __bf16* xbf  = (__bf16*)((char*)d_ws + XBF_OFF);
    float*  cv   = (float*)((char*)d_ws + CV_OFF);

    prep_weights<<<4608, 256, 0, stream>>>(kern, wt);
    zero_fill<<<64, 256, 0, stream>>>((float*)zrow);
    prep_x<<<8192, 256, 0, stream>>>(x, xbf, xtb);

    if (ws_size >= WS_NEED_SPLIT) {
        conv_coords<<<4096, 256, 0, stream>>>(xbf, zrow, wt, bias, cv);
        gather_out<<<1024, 1024, 0, stream>>>(cv, xtb, out);
    } else {
        conv_offset_sample<<<4096, 256, 0, stream>>>(xbf, xtb, zrow, wt, bias, out);
    }
}